// Round 12
// baseline (60.285 us; speedup 1.0000x reference)
//
#include <hip/hip_runtime.h>
#include <math.h>

// Problem constants (from reference)
constexpr int kC   = 3;
constexpr int kTIn = 2048;
constexpr int kR   = 64;
constexpr int kTB  = 128;
constexpr float kAlpha = 10.0f;
constexpr float kLog2e = 1.44269504088896f;

constexpr int kSampleF = kC * kTIn;       // 6144 floats = 24 KB per sample
constexpr int kGrid    = 768;             // 3 blocks/CU exactly

#ifndef __has_builtin
#define __has_builtin(x) 0
#endif

static __device__ __forceinline__ float fast_rcp(float x) {
#if __has_builtin(__builtin_amdgcn_rcpf)
    return __builtin_amdgcn_rcpf(x);
#else
    return 1.0f / x;
#endif
}

static __device__ __forceinline__ float fast_exp2(float x) {
#if __has_builtin(__builtin_amdgcn_exp2f)
    return __builtin_amdgcn_exp2f(x);
#else
    return __builtin_exp2f(x);
#endif
}

// ---------------------------------------------------------------------------
// DMA-pipelined producer/consumer. 4 waves/block: waves 0-2 = poolers
// (fixed role; each owns 8 of the 24 1-KB chunks/sample), wave 3 = scanner
// (never issues global_load_lds -> its scan can't pick up conservative
// vmcnt waits). raw[2] double buffer: DMA for sample k+2 issues at the TOP
// of iteration k -> >=8 chunks/wave in flight across every barrier
// (counted vmcnt(8), never drained to 0 in the loop).
// Per iteration (one raw s_barrier, lgkm-only wait):
//   poolers: dma(k+2 -> raw[k&1]); vmcnt(8); pool raw[(k+1)&1] -> sp,red
//   scanner: scan sp[k&1] (params precomputed in prologue shadow); store
// ---------------------------------------------------------------------------
__global__ __launch_bounds__(256, 3)
void fused_encoder_kernel(const float* __restrict__ traces,
                          const float* __restrict__ drive_w,
                          const float* __restrict__ drive_b,
                          const float* __restrict__ freq_raw,
                          const float* __restrict__ q_raw,
                          const float* __restrict__ thr_raw,
                          float* __restrict__ out,
                          int kSmall, int rem)
{
    __shared__ float raw[2][kSampleF];   // 48 KB
    __shared__ float sp[2][kTB * 4];     // 4 KB  [buf][t*4+c]
    __shared__ float red[2][3];

    const int tid  = threadIdx.x;
    const int wave = tid >> 6;
    const int lane = tid & 63;

    // contiguous sample range per block (blocks < rem get one extra)
    const int bx = blockIdx.x;
    int K; long long base;
    if (bx < rem) { K = kSmall + 1; base = (long long)bx * K; }
    else          { K = kSmall;     base = (long long)rem * (kSmall + 1)
                                         + (long long)(bx - rem) * kSmall; }

    if (wave < 3) {
        // ===================== pooler p = wave =====================
        const int p = wave;

        auto dma = [&](long long s, int buf) {
            const float* src = traces + s * kSampleF + p * 2048 + lane * 4;
            float* dst = &raw[buf][p * 2048];
            #pragma unroll
            for (int j = 0; j < 8; ++j) {
                __builtin_amdgcn_global_load_lds(
                    (const __attribute__((address_space(1))) void*)(src + j * 256),
                    (__attribute__((address_space(3))) void*)(dst + j * 256),
                    16, 0, 0);
            }
        };
        auto pool = [&](int buf) {
            const float4* r4 = reinterpret_cast<const float4*>(raw[buf]);
            float mloc = 0.0f;
            #pragma unroll
            for (int j2 = 0; j2 < 8; ++j2) {
                const int j = p * 8 + j2;
                float4 v = r4[j * 64 + lane];            // ds_read_b128
                float s = (v.x + v.y) + (v.z + v.w);
                s += __shfl_xor(s, 1, 64);
                s += __shfl_xor(s, 2, 64);               // window sum in quad
                mloc = fmaxf(mloc, fabsf(s));
                if ((lane & 3) == 0) {
                    int w = j * 16 + (lane >> 2);        // w = c*128 + t
                    sp[buf][(w & 127) * 4 + (w >> 7)] = s;
                }
            }
            #pragma unroll
            for (int off = 4; off <= 32; off <<= 1)      // quads already uniform
                mloc = fmaxf(mloc, __shfl_xor(mloc, off, 64));
            if (lane == 0) red[buf][p] = mloc;
        };

        // prologue: samples 0,1 into flight; pool sample 0
        dma(base + 0, 0);
        if (K > 1) dma(base + 1, 1);
        asm volatile("s_waitcnt vmcnt(8)" ::: "memory");   // sample 0 landed
        pool(0);
        asm volatile("s_waitcnt lgkmcnt(0)\n\ts_barrier" ::: "memory");

        for (int k = 0; k < K; ++k) {
            if (k + 2 < K) {
                dma(base + k + 2, k & 1);                  // refill queue FIRST
                asm volatile("s_waitcnt vmcnt(8)" ::: "memory"); // k+1 landed
            } else {
                asm volatile("s_waitcnt vmcnt(0)" ::: "memory"); // drain tail
            }
            if (k + 1 < K) pool((k + 1) & 1);
            asm volatile("s_waitcnt lgkmcnt(0)\n\ts_barrier" ::: "memory");
        }
    } else {
        // ===================== scanner =====================
        const int r = lane;
        const float w0   = drive_w[r * kC + 0];
        const float w1   = drive_w[r * kC + 1];
        const float w2   = drive_w[r * kC + 2];
        const float bias = drive_b[r];
        const float freq  = 0.03f + 0.17f / (1.0f + expf(-freq_raw[r]));
        const float qf    = 1.5f + log1pf(expf(q_raw[r]));
        const float decay = expf(-1.0f / qf);
        const float thr   = 0.35f + 0.75f / (1.0f + expf(-thr_raw[r]));
        const float expScale = kAlpha * kLog2e;
        const float thrE  = thr * expScale;

        asm volatile("s_barrier" ::: "memory");            // matches prologue
        for (int k = 0; k < K; ++k) {
            const int cur = k & 1;
            const float mm = fmaxf(fmaxf(red[cur][0], red[cur][1]), red[cur][2]);
            const float inv = fast_rcp(fmaxf(mm * (1.0f / 16.0f), 1.0f)) * (1.0f / 16.0f);
            const float v0 = w0 * inv, v1 = w1 * inv, v2 = w2 * inv;
            const float4* pt = reinterpret_cast<const float4*>(sp[cur]);

            __builtin_amdgcn_s_setprio(1);
            float state = 0.0f, vel = 0.0f, acc = 0.0f;
            #pragma unroll 8
            for (int t = 0; t < kTB; ++t) {
                float4 pv = pt[t];                         // broadcast ds_read_b128
                float cur_ = fmaf(pv.x, v0, bias);
                cur_ = fmaf(pv.y, v1, cur_);
                cur_ = fmaf(pv.z, v2, cur_);
                vel = fmaf(decay, vel, cur_);
                vel = fmaf(-freq, state, vel);
                state = fmaf(freq, vel, state);
                float e = fast_exp2(fmaf(-expScale, state, thrE));
                float spike = fast_rcp(1.0f + e);
                state = fmaf(-spike, thr, state);
                acc += spike;
            }
            __builtin_amdgcn_s_setprio(0);

            out[(base + k) * kR + r] = acc * (1.0f / kTB);
            asm volatile("s_barrier" ::: "memory");
        }
    }
}

extern "C" void kernel_launch(void* const* d_in, const int* in_sizes, int n_in,
                              void* d_out, int out_size, void* d_ws, size_t ws_size,
                              hipStream_t stream)
{
    const float* traces   = (const float*)d_in[0];
    const float* drive_w  = (const float*)d_in[1];
    const float* drive_b  = (const float*)d_in[2];
    const float* freq_raw = (const float*)d_in[3];
    const float* q_raw    = (const float*)d_in[4];
    const float* thr_raw  = (const float*)d_in[5];
    float* out = (float*)d_out;

    const int totalB = in_sizes[0] / kSampleF;     // 8192
    const int kSmall = totalB / kGrid;             // 10
    const int rem    = totalB % kGrid;             // 512

    fused_encoder_kernel<<<kGrid, 256, 0, stream>>>(traces, drive_w, drive_b,
                                                    freq_raw, q_raw, thr_raw,
                                                    out, kSmall, rem);
}

// Round 13
// 51.134 us; speedup vs baseline: 1.1790x; 1.1790x over previous
//
#include <hip/hip_runtime.h>
#include <math.h>

// Problem constants (from reference)
constexpr int kC   = 3;
constexpr int kTIn = 2048;
constexpr int kR   = 64;
constexpr int kTB  = 128;
constexpr float kAlpha = 10.0f;
constexpr float kLog2e = 1.44269504088896f;

constexpr int kK   = 2;              // samples per block (2 generations of blocks)
constexpr int kF4  = kC * kTIn / 4;  // 1536 float4 per sample

#ifndef __has_builtin
#define __has_builtin(x) 0
#endif

static __device__ __forceinline__ float fast_rcp(float x) {
#if __has_builtin(__builtin_amdgcn_rcpf)
    return __builtin_amdgcn_rcpf(x);
#else
    return 1.0f / x;
#endif
}

static __device__ __forceinline__ float fast_exp2(float x) {
#if __has_builtin(__builtin_amdgcn_exp2f)
    return __builtin_amdgcn_exp2f(x);
#else
    return __builtin_exp2f(x);
#endif
}

// ---------------------------------------------------------------------------
// Wave-specialized producer/consumer (round-10 structure, K=2, grid=2 gens).
// 4 waves/block; 4096 blocks -> 2 generations of residency. A retiring
// block's scan-only tail is back-filled by the next generation's prologue
// loads, so the memory queue stays fed end-to-end (R10's exposed ~4.5us
// tail was the main residue over the ~33us stream floor).
//   helpers (3 waves): load+pool sample -> sp[buf], wave-max -> red[buf]
//   scanner (1 wave, = blockIdx&3): params in prologue shadow, then scans.
// Plain __syncthreads; no hand fences (R8/R9/R12 regression lessons).
// ---------------------------------------------------------------------------
__global__ __launch_bounds__(256, 8)
void fused_encoder_kernel(const float* __restrict__ traces,
                          const float* __restrict__ drive_w,
                          const float* __restrict__ drive_b,
                          const float* __restrict__ freq_raw,
                          const float* __restrict__ q_raw,
                          const float* __restrict__ thr_raw,
                          float* __restrict__ out)
{
    __shared__ float sp[2][kTB * 4];   // [buf][t*4+c], 4 KB
    __shared__ float red[2][3];        // per-helper-wave maxes

    const int tid  = threadIdx.x;
    const int wave = tid >> 6;
    const int lane = tid & 63;
    const int scanWave = blockIdx.x & 3;
    const long long base = (long long)blockIdx.x * kK;
    const float4* tr4 = reinterpret_cast<const float4*>(traces);

    if (wave != scanWave) {
        // ================= helper: load + pool + max =================
        const int h = wave - (wave > scanWave ? 1 : 0);   // 0..2

        auto pool = [&](long long b, int buf) {
            const float4* src = tr4 + b * kF4 + (h * 8) * 64 + lane;
            float mloc = 0.0f;
            #pragma unroll
            for (int j = 0; j < 8; ++j) {
                float4 v = src[j * 64];                   // coalesced 1 KB/inst
                float s = (v.x + v.y) + (v.z + v.w);
                s += __shfl_xor(s, 1, 64);
                s += __shfl_xor(s, 2, 64);                // window sum in quad
                mloc = fmaxf(mloc, fabsf(s));
                if ((lane & 3) == 0) {
                    int w = (h * 8 + j) * 16 + (lane >> 2);   // w = c*128 + t
                    sp[buf][(w & 127) * 4 + (w >> 7)] = s;
                }
            }
            #pragma unroll
            for (int off = 4; off <= 32; off <<= 1)       // quads already uniform
                mloc = fmaxf(mloc, __shfl_xor(mloc, off, 64));
            if (lane == 0) red[buf][h] = mloc;
        };

        pool(base, 0);                 // prologue: sample 0 -> buf 0
        __syncthreads();
        for (int k = 0; k < kK; ++k) {
            if (k + 1 < kK) pool(base + k + 1, (k + 1) & 1);
            __syncthreads();
        }
    } else {
        // ========== scanner: params (hidden under helpers' pool) + scans ====
        const int r = lane;
        const float w0   = drive_w[r * kC + 0];
        const float w1   = drive_w[r * kC + 1];
        const float w2   = drive_w[r * kC + 2];
        const float bias = drive_b[r];
        const float freq  = 0.03f + 0.17f / (1.0f + expf(-freq_raw[r]));
        const float qf    = 1.5f + log1pf(expf(q_raw[r]));
        const float decay = expf(-1.0f / qf);
        const float thr   = 0.35f + 0.75f / (1.0f + expf(-thr_raw[r]));
        const float expScale = kAlpha * kLog2e;
        const float thrE  = thr * expScale;

        __syncthreads();
        for (int k = 0; k < kK; ++k) {
            const int cur = k & 1;
            const float mm = fmaxf(fmaxf(red[cur][0], red[cur][1]), red[cur][2]);
            const float inv = fast_rcp(fmaxf(mm * (1.0f / 16.0f), 1.0f)) * (1.0f / 16.0f);
            const float v0 = w0 * inv, v1 = w1 * inv, v2 = w2 * inv;
            const float4* pt = reinterpret_cast<const float4*>(sp[cur]);

            __builtin_amdgcn_s_setprio(1);
            float state = 0.0f, vel = 0.0f, acc = 0.0f;
            #pragma unroll 8
            for (int t = 0; t < kTB; ++t) {
                float4 p = pt[t];                     // broadcast ds_read_b128
                float cur_ = fmaf(p.x, v0, bias);
                cur_ = fmaf(p.y, v1, cur_);
                cur_ = fmaf(p.z, v2, cur_);
                vel = fmaf(decay, vel, cur_);
                vel = fmaf(-freq, state, vel);
                state = fmaf(freq, vel, state);
                float e = fast_exp2(fmaf(-expScale, state, thrE));
                float spike = fast_rcp(1.0f + e);
                state = fmaf(-spike, thr, state);
                acc += spike;
            }
            __builtin_amdgcn_s_setprio(0);

            out[(base + k) * kR + r] = acc * (1.0f / kTB);
            __syncthreads();
        }
    }
}

extern "C" void kernel_launch(void* const* d_in, const int* in_sizes, int n_in,
                              void* d_out, int out_size, void* d_ws, size_t ws_size,
                              hipStream_t stream)
{
    const float* traces   = (const float*)d_in[0];
    const float* drive_w  = (const float*)d_in[1];
    const float* drive_b  = (const float*)d_in[2];
    const float* freq_raw = (const float*)d_in[3];
    const float* q_raw    = (const float*)d_in[4];
    const float* thr_raw  = (const float*)d_in[5];
    float* out = (float*)d_out;

    const int totalB = in_sizes[0] / (kC * kTIn);   // 8192
    const int grid = totalB / kK;                   // 4096 blocks = 2 generations

    fused_encoder_kernel<<<grid, 256, 0, stream>>>(traces, drive_w, drive_b,
                                                   freq_raw, q_raw, thr_raw, out);
}

// Round 14
// 39.919 us; speedup vs baseline: 1.5102x; 1.2810x over previous
//
#include <hip/hip_runtime.h>
#include <math.h>

// Problem constants (from reference)
constexpr int kC   = 3;
constexpr int kTIn = 2048;
constexpr int kR   = 64;
constexpr int kTB  = 128;
constexpr float kAlpha = 10.0f;
constexpr float kLog2e = 1.44269504088896f;

constexpr int kK   = 4;              // samples per block
constexpr int kF4  = kC * kTIn / 4;  // 1536 float4 per sample

#ifndef __has_builtin
#define __has_builtin(x) 0
#endif

static __device__ __forceinline__ float fast_rcp(float x) {
#if __has_builtin(__builtin_amdgcn_rcpf)
    return __builtin_amdgcn_rcpf(x);
#else
    return 1.0f / x;
#endif
}

static __device__ __forceinline__ float fast_exp2(float x) {
#if __has_builtin(__builtin_amdgcn_exp2f)
    return __builtin_amdgcn_exp2f(x);
#else
    return __builtin_exp2f(x);
#endif
}

// ---------------------------------------------------------------------------
// Wave-specialized producer/consumer block (round-10 configuration — the
// session's best at 40.1 us). Plain __syncthreads handoff, monolithic pool,
// NO hand-placed fences: the compiler's own progressive load/consume
// scheduling beat every explicit pipeline variant (R5/R8/R9/R12/R13).
// 4 waves/block, K=4 samples, 2048 blocks fully resident (32 waves/CU).
//   helpers (3 waves): load+pool sample k+1 -> sp[nxt], wave-max -> red[nxt]
//   scanner (1 wave, = blockIdx&3 to spread across SIMDs): resonator params
//     computed in the prologue shadow, then scans sp[cur] each iteration.
// ---------------------------------------------------------------------------
__global__ __launch_bounds__(256, 8)
void fused_encoder_kernel(const float* __restrict__ traces,
                          const float* __restrict__ drive_w,
                          const float* __restrict__ drive_b,
                          const float* __restrict__ freq_raw,
                          const float* __restrict__ q_raw,
                          const float* __restrict__ thr_raw,
                          float* __restrict__ out)
{
    __shared__ float sp[2][kTB * 4];   // [buf][t*4+c], 4 KB
    __shared__ float red[2][3];        // per-helper-wave maxes

    const int tid  = threadIdx.x;
    const int wave = tid >> 6;
    const int lane = tid & 63;
    const int scanWave = blockIdx.x & 3;
    const long long base = (long long)blockIdx.x * kK;
    const float4* tr4 = reinterpret_cast<const float4*>(traces);

    if (wave != scanWave) {
        // ================= helper: load + pool + max =================
        const int h = wave - (wave > scanWave ? 1 : 0);   // 0..2

        auto pool = [&](long long b, int buf) {
            const float4* src = tr4 + b * kF4 + (h * 8) * 64 + lane;
            float mloc = 0.0f;
            #pragma unroll
            for (int j = 0; j < 8; ++j) {
                float4 v = src[j * 64];                   // coalesced 1 KB/inst
                float s = (v.x + v.y) + (v.z + v.w);
                s += __shfl_xor(s, 1, 64);
                s += __shfl_xor(s, 2, 64);                // window sum in quad
                mloc = fmaxf(mloc, fabsf(s));
                if ((lane & 3) == 0) {
                    int w = (h * 8 + j) * 16 + (lane >> 2);   // w = c*128 + t
                    sp[buf][(w & 127) * 4 + (w >> 7)] = s;
                }
            }
            #pragma unroll
            for (int off = 4; off <= 32; off <<= 1)       // quads already uniform
                mloc = fmaxf(mloc, __shfl_xor(mloc, off, 64));
            if (lane == 0) red[buf][h] = mloc;
        };

        pool(base, 0);                 // prologue: sample 0 -> buf 0
        __syncthreads();
        for (int k = 0; k < kK; ++k) {
            if (k + 1 < kK) pool(base + k + 1, (k + 1) & 1);
            __syncthreads();
        }
    } else {
        // ========== scanner: params (hidden under helpers' pool) + scans ====
        const int r = lane;
        const float w0   = drive_w[r * kC + 0];
        const float w1   = drive_w[r * kC + 1];
        const float w2   = drive_w[r * kC + 2];
        const float bias = drive_b[r];
        const float freq  = 0.03f + 0.17f / (1.0f + expf(-freq_raw[r]));
        const float qf    = 1.5f + log1pf(expf(q_raw[r]));
        const float decay = expf(-1.0f / qf);
        const float thr   = 0.35f + 0.75f / (1.0f + expf(-thr_raw[r]));
        const float expScale = kAlpha * kLog2e;
        const float thrE  = thr * expScale;

        __syncthreads();
        for (int k = 0; k < kK; ++k) {
            const int cur = k & 1;
            const float mm = fmaxf(fmaxf(red[cur][0], red[cur][1]), red[cur][2]);
            const float inv = fast_rcp(fmaxf(mm * (1.0f / 16.0f), 1.0f)) * (1.0f / 16.0f);
            const float v0 = w0 * inv, v1 = w1 * inv, v2 = w2 * inv;
            const float4* pt = reinterpret_cast<const float4*>(sp[cur]);

            __builtin_amdgcn_s_setprio(1);
            float state = 0.0f, vel = 0.0f, acc = 0.0f;
            #pragma unroll 8
            for (int t = 0; t < kTB; ++t) {
                float4 p = pt[t];                     // broadcast ds_read_b128
                float cur_ = fmaf(p.x, v0, bias);
                cur_ = fmaf(p.y, v1, cur_);
                cur_ = fmaf(p.z, v2, cur_);
                vel = fmaf(decay, vel, cur_);
                vel = fmaf(-freq, state, vel);
                state = fmaf(freq, vel, state);
                float e = fast_exp2(fmaf(-expScale, state, thrE));
                float spike = fast_rcp(1.0f + e);
                state = fmaf(-spike, thr, state);
                acc += spike;
            }
            __builtin_amdgcn_s_setprio(0);

            out[(base + k) * kR + r] = acc * (1.0f / kTB);
            __syncthreads();
        }
    }
}

extern "C" void kernel_launch(void* const* d_in, const int* in_sizes, int n_in,
                              void* d_out, int out_size, void* d_ws, size_t ws_size,
                              hipStream_t stream)
{
    const float* traces   = (const float*)d_in[0];
    const float* drive_w  = (const float*)d_in[1];
    const float* drive_b  = (const float*)d_in[2];
    const float* freq_raw = (const float*)d_in[3];
    const float* q_raw    = (const float*)d_in[4];
    const float* thr_raw  = (const float*)d_in[5];
    float* out = (float*)d_out;

    const int totalB = in_sizes[0] / (kC * kTIn);   // 8192
    const int grid = totalB / kK;                   // 2048 blocks, fully resident

    fused_encoder_kernel<<<grid, 256, 0, stream>>>(traces, drive_w, drive_b,
                                                   freq_raw, q_raw, thr_raw, out);
}